// Round 5
// baseline (1527.861 us; speedup 1.0000x reference)
//
#include <hip/hip_runtime.h>

// GCNConv forward: out = segment_sum(vals * (x@W)[cols], rows) + bias
// Round 5: drop row-exact CSR (fill_csr had 8x write amplification, 100MB for
// 12.8MB). Coarse 64-row buckets with per-(bucket,slot) append regions
// (slot = blockIdx&7, XCD-local so partial lines merge in one L2), then
// bucket_gather accumulates into a 32KB LDS fp32 tile and writes densely.
//
// ws: h[N*128] bf16 | wt[128*264] bf16 | counts2[NB*8] | offsets2[NB*8+1] |
//     cursor2[NB*8] | bcv[E] int2 (col | rowoff<<17, val) | bsum | bpre

typedef __attribute__((ext_vector_type(8))) short short8;
typedef __attribute__((ext_vector_type(4))) float floatx4;

#define WT_K 264
#define GM_NODES 128
#define SCAN_CHUNK 1024
#define BSHIFT 6              // 64 rows per bucket
#define BROWS 64

static __device__ __forceinline__ uint f2bf(float x) {  // RNE f32->bf16 bits
  uint u = __float_as_uint(x);
  return (u + 0x7fffu + ((u >> 16) & 1u)) >> 16;
}

// ---- W[k][f] f32 -> wt[f][k] bf16 (k padded to WT_K) ----
__global__ __launch_bounds__(256) void conv_w(const float* __restrict__ w,
                                              ushort* __restrict__ wt) {
  const int f = blockIdx.x;
  const int k = threadIdx.x;
  wt[f * WT_K + k] = (ushort)f2bf(w[k * 128 + f]);
}

// ---- GEMM: h^T = W^T x^T via 16x16x32 bf16 MFMA (unchanged from R4) ----
__global__ __launch_bounds__(256) void gemm_mfma(const float* __restrict__ x,
                                                 const ushort* __restrict__ wt,
                                                 ushort* __restrict__ h,
                                                 int n_nodes) {
  __shared__ ushort lw[128 * WT_K];
  __shared__ ushort xa[GM_NODES * 40];
  const int t = threadIdx.x;
  const int lane = t & 63;
  const int wq = t >> 6;
  const int quad = lane >> 4;
  const int l15 = lane & 15;
  const int row0 = blockIdx.x * GM_NODES;

  {
    const uint4* src = (const uint4*)wt;
    uint4* dst = (uint4*)lw;
    for (int i = t; i < (128 * WT_K * 2) / 16; i += 256) dst[i] = src[i];
  }

  floatx4 acc[2][8];
#pragma unroll
  for (int nt = 0; nt < 2; ++nt)
#pragma unroll
    for (int mt = 0; mt < 8; ++mt) acc[nt][mt] = (floatx4){0.f, 0.f, 0.f, 0.f};

  float4 cur[4];
#pragma unroll
  for (int i = 0; i < 4; ++i) {
    const int idx = i * 256 + t;
    const int row = idx >> 3, kq = idx & 7;
    const int gr = row0 + row;
    cur[i] = (gr < n_nodes) ? *(const float4*)&x[(size_t)gr * 256 + kq * 4]
                            : make_float4(0.f, 0.f, 0.f, 0.f);
  }

  for (int kc = 0; kc < 8; ++kc) {
#pragma unroll
    for (int i = 0; i < 4; ++i) {
      const int idx = i * 256 + t;
      const int row = idx >> 3, kq = idx & 7;
      uint2 p;
      p.x = f2bf(cur[i].x) | (f2bf(cur[i].y) << 16);
      p.y = f2bf(cur[i].z) | (f2bf(cur[i].w) << 16);
      *(uint2*)&xa[row * 40 + kq * 4] = p;
    }
    __syncthreads();

    float4 nxt[4];
    if (kc < 7) {
#pragma unroll
      for (int i = 0; i < 4; ++i) {
        const int idx = i * 256 + t;
        const int row = idx >> 3, kq = idx & 7;
        const int gr = row0 + row;
        nxt[i] = (gr < n_nodes)
                     ? *(const float4*)&x[(size_t)gr * 256 + (kc + 1) * 32 + kq * 4]
                     : make_float4(0.f, 0.f, 0.f, 0.f);
      }
    }

    short8 bfr[2];
    bfr[0] = *(const short8*)&xa[(wq * 32 + l15) * 40 + quad * 8];
    bfr[1] = *(const short8*)&xa[(wq * 32 + 16 + l15) * 40 + quad * 8];
#pragma unroll
    for (int mt = 0; mt < 8; ++mt) {
      const short8 afr =
          *(const short8*)&lw[(mt * 16 + l15) * WT_K + kc * 32 + quad * 8];
      acc[0][mt] = __builtin_amdgcn_mfma_f32_16x16x32_bf16(afr, bfr[0],
                                                           acc[0][mt], 0, 0, 0);
      acc[1][mt] = __builtin_amdgcn_mfma_f32_16x16x32_bf16(afr, bfr[1],
                                                           acc[1][mt], 0, 0, 0);
    }
    __syncthreads();
#pragma unroll
    for (int i = 0; i < 4; ++i) cur[i] = nxt[i];
  }

#pragma unroll
  for (int nt = 0; nt < 2; ++nt) {
    const int node = row0 + wq * 32 + nt * 16 + l15;
    if (node < n_nodes) {
#pragma unroll
      for (int mt = 0; mt < 8; ++mt) {
        uint2 p;
        p.x = f2bf(acc[nt][mt][0]) | (f2bf(acc[nt][mt][1]) << 16);
        p.y = f2bf(acc[nt][mt][2]) | (f2bf(acc[nt][mt][3]) << 16);
        *(uint2*)&h[(size_t)node * 128 + mt * 16 + quad * 4] = p;
      }
    }
  }
}

// ---- bucket histogram: counts2[(row>>6)*8 + blockIdx&7] ----
__global__ __launch_bounds__(256) void hist2(const int* __restrict__ erows,
                                             int* __restrict__ counts2,
                                             int n_edges) {
  int i = blockIdx.x * 256 + threadIdx.x;
  if (i < n_edges) {
    int slot = blockIdx.x & 7;
    atomicAdd(&counts2[((erows[i] >> BSHIFT) << 3) | slot], 1);
  }
}

// ---- 3-phase scan (reused machinery) ----
__global__ __launch_bounds__(256) void reduce_chunks(const int* __restrict__ counts,
                                                     int* __restrict__ bsum, int n) {
  const int b = blockIdx.x;
  const int t = threadIdx.x;
  const int base = b * SCAN_CHUNK + t * 4;
  int s = 0;
  if (base + 4 <= n) {
    int4 v = *(const int4*)&counts[base];
    s = v.x + v.y + v.z + v.w;
  } else {
    for (int i = base; i < n; ++i) s += counts[i];
  }
#pragma unroll
  for (int off = 32; off; off >>= 1) s += __shfl_down(s, off, 64);
  __shared__ int wsum[4];
  if ((t & 63) == 0) wsum[t >> 6] = s;
  __syncthreads();
  if (t == 0) bsum[b] = wsum[0] + wsum[1] + wsum[2] + wsum[3];
}

__global__ __launch_bounds__(128) void scan_bsums(const int* __restrict__ bsum,
                                                  int* __restrict__ bpre,
                                                  int* __restrict__ offsets,
                                                  int nb, int n) {
  __shared__ int s[128];
  const int t = threadIdx.x;
  int v = (t < nb) ? bsum[t] : 0;
  s[t] = v;
  __syncthreads();
  for (int off = 1; off < 128; off <<= 1) {
    int u = (t >= off) ? s[t - off] : 0;
    __syncthreads();
    s[t] += u;
    __syncthreads();
  }
  if (t < nb) bpre[t] = s[t] - v;
  if (t == 0) offsets[n] = s[127];
}

__global__ __launch_bounds__(256) void write_offsets(const int* __restrict__ counts,
                                                     const int* __restrict__ bpre,
                                                     int* __restrict__ offsets,
                                                     int* __restrict__ cursor, int n) {
  const int b = blockIdx.x;
  const int t = threadIdx.x;
  const int base = b * SCAN_CHUNK + t * 4;
  int c0 = 0, c1 = 0, c2 = 0, c3 = 0;
  if (base + 4 <= n) {
    int4 v = *(const int4*)&counts[base];
    c0 = v.x; c1 = v.y; c2 = v.z; c3 = v.w;
  } else {
    if (base + 0 < n) c0 = counts[base + 0];
    if (base + 1 < n) c1 = counts[base + 1];
    if (base + 2 < n) c2 = counts[base + 2];
    if (base + 3 < n) c3 = counts[base + 3];
  }
  const int mysum = c0 + c1 + c2 + c3;
  __shared__ int sums[256];
  sums[t] = mysum;
  __syncthreads();
  for (int off = 1; off < 256; off <<= 1) {
    int u = (t >= off) ? sums[t - off] : 0;
    __syncthreads();
    sums[t] += u;
    __syncthreads();
  }
  int pre = bpre[b] + sums[t] - mysum;
  if (base + 0 < n) { offsets[base + 0] = pre; cursor[base + 0] = pre; pre += c0; }
  if (base + 1 < n) { offsets[base + 1] = pre; cursor[base + 1] = pre; pre += c1; }
  if (base + 2 < n) { offsets[base + 2] = pre; cursor[base + 2] = pre; pre += c2; }
  if (base + 3 < n) { offsets[base + 3] = pre; cursor[base + 3] = pre; pre += c3; }
}

// ---- append edges into (bucket,slot) regions; rowoff packed into col word ----
__global__ __launch_bounds__(256) void fill_buckets(
    const int* __restrict__ erows, const int* __restrict__ ecols,
    const float* __restrict__ evals, int* __restrict__ cursor2,
    int2* __restrict__ bcv, int n_edges) {
  int i = blockIdx.x * 256 + threadIdx.x;
  if (i < n_edges) {
    int slot = blockIdx.x & 7;
    int r = erows[i];
    int idx = ((r >> BSHIFT) << 3) | slot;
    int pos = atomicAdd(&cursor2[idx], 1);
    int2 p;
    p.x = ecols[i] | ((r & (BROWS - 1)) << 17);
    p.y = __float_as_int(evals[i]);
    bcv[pos] = p;
  }
}

// ---- bucket gather: LDS fp32 accumulator for 64 rows x 128 feats ----
__global__ __launch_bounds__(256) void bucket_gather(
    const ushort* __restrict__ h, const int* __restrict__ offsets2,
    const int2* __restrict__ bcv, const float* __restrict__ bias,
    float* __restrict__ out, int n_nodes) {
  __shared__ float acc[BROWS * 128];   // 32 KB
  const int b = blockIdx.x;
  const int t = threadIdx.x;
  for (int i = t; i < BROWS * 128 / 4; i += 256)
    ((float4*)acc)[i] = make_float4(0.f, 0.f, 0.f, 0.f);
  __syncthreads();

  const int lane = t & 63;
  const int w = t >> 6;
  const int p0 = offsets2[b * 8];
  const int p1 = offsets2[b * 8 + 8];

  for (int base = p0 + w * 4; base < p1; base += 16) {
    if (base + 4 <= p1) {
      int2 c0 = bcv[base + 0];
      int2 c1 = bcv[base + 1];
      int2 c2 = bcv[base + 2];
      int2 c3 = bcv[base + 3];
      uint u0 = ((const uint*)(h + (size_t)(c0.x & 0x1FFFF) * 128))[lane];
      uint u1 = ((const uint*)(h + (size_t)(c1.x & 0x1FFFF) * 128))[lane];
      uint u2 = ((const uint*)(h + (size_t)(c2.x & 0x1FFFF) * 128))[lane];
      uint u3 = ((const uint*)(h + (size_t)(c3.x & 0x1FFFF) * 128))[lane];
      float v0 = __int_as_float(c0.y), v1 = __int_as_float(c1.y);
      float v2 = __int_as_float(c2.y), v3 = __int_as_float(c3.y);
      float* a0 = &acc[(uint)(c0.x >> 17) * 128 + lane * 2];
      float* a1 = &acc[(uint)(c1.x >> 17) * 128 + lane * 2];
      float* a2 = &acc[(uint)(c2.x >> 17) * 128 + lane * 2];
      float* a3 = &acc[(uint)(c3.x >> 17) * 128 + lane * 2];
      atomicAdd(a0 + 0, v0 * __uint_as_float(u0 << 16));
      atomicAdd(a0 + 1, v0 * __uint_as_float(u0 & 0xffff0000u));
      atomicAdd(a1 + 0, v1 * __uint_as_float(u1 << 16));
      atomicAdd(a1 + 1, v1 * __uint_as_float(u1 & 0xffff0000u));
      atomicAdd(a2 + 0, v2 * __uint_as_float(u2 << 16));
      atomicAdd(a2 + 1, v2 * __uint_as_float(u2 & 0xffff0000u));
      atomicAdd(a3 + 0, v3 * __uint_as_float(u3 << 16));
      atomicAdd(a3 + 1, v3 * __uint_as_float(u3 & 0xffff0000u));
    } else {
      for (int p = base; p < p1; ++p) {
        int2 c = bcv[p];
        uint u = ((const uint*)(h + (size_t)(c.x & 0x1FFFF) * 128))[lane];
        float v = __int_as_float(c.y);
        float* a = &acc[(uint)(c.x >> 17) * 128 + lane * 2];
        atomicAdd(a + 0, v * __uint_as_float(u << 16));
        atomicAdd(a + 1, v * __uint_as_float(u & 0xffff0000u));
      }
    }
  }
  __syncthreads();

  const int row0 = b * BROWS;
  for (int i = t; i < BROWS * 32; i += 256) {   // 32 float4 per row
    int r = i >> 5;
    int f4 = i & 31;
    int grow = row0 + r;
    if (grow < n_nodes) {
      float4 a4 = ((float4*)acc)[i];
      float4 b4 = ((const float4*)bias)[f4];
      a4.x += b4.x; a4.y += b4.y; a4.z += b4.z; a4.w += b4.w;
      ((float4*)&out[(size_t)grow * 128])[f4] = a4;
    }
  }
}

// ---- fallback (small ws): bias init + atomic scatter on bf16 h ----
__global__ __launch_bounds__(256) void init_bias(float* __restrict__ out,
                                                 const float* __restrict__ bias,
                                                 int n4) {
  int i = blockIdx.x * 256 + threadIdx.x;
  if (i < n4) {
    float4 b = ((const float4*)bias)[i & 31];
    ((float4*)out)[i] = b;
  }
}

__global__ __launch_bounds__(256) void scatter_edges(
    const ushort* __restrict__ h, const int* __restrict__ erows,
    const int* __restrict__ ecols, const float* __restrict__ evals,
    float* __restrict__ out, int n_edges) {
  int e = blockIdx.x * 4 + (threadIdx.x >> 6);
  if (e >= n_edges) return;
  int lane = threadIdx.x & 63;
  int row = erows[e];
  int col = ecols[e];
  float v = evals[e];
  uint u = ((const uint*)(h + (size_t)col * 128))[lane];
  float* op = out + (size_t)row * 128 + lane * 2;
  atomicAdd(op, v * __uint_as_float(u << 16));
  atomicAdd(op + 1, v * __uint_as_float(u & 0xffff0000u));
}

extern "C" void kernel_launch(void* const* d_in, const int* in_sizes, int n_in,
                              void* d_out, int out_size, void* d_ws, size_t ws_size,
                              hipStream_t stream) {
  const float* x     = (const float*)d_in[0];
  const int*   erows = (const int*)d_in[1];
  const int*   ecols = (const int*)d_in[2];
  const float* evals = (const float*)d_in[3];
  const float* w     = (const float*)d_in[4];
  const float* bias  = (const float*)d_in[5];
  float* out = (float*)d_out;

  const int n_nodes = in_sizes[0] / 256;
  const int n_edges = in_sizes[1];
  const int nb_buckets = (n_nodes + BROWS - 1) >> BSHIFT;
  const int nb8 = nb_buckets * 8;

  // ws carve-up (16B aligned)
  char* ws = (char*)d_ws;
  size_t off = 0;
  ushort* h  = (ushort*)(ws + off);  off += ((size_t)n_nodes * 128 * 2 + 15) & ~15ull;
  ushort* wt = (ushort*)(ws + off);  off += ((size_t)128 * WT_K * 2 + 15) & ~15ull;
  int* counts2  = (int*)(ws + off);  off += ((size_t)nb8 * 4 + 15) & ~15ull;
  int* offsets2 = (int*)(ws + off);  off += ((size_t)(nb8 + 1) * 4 + 15) & ~15ull;
  int* cursor2  = (int*)(ws + off);  off += ((size_t)nb8 * 4 + 15) & ~15ull;
  int2* bcv     = (int2*)(ws + off); off += (size_t)n_edges * 8;
  int* bsum     = (int*)(ws + off);  off += 128 * 4;
  int* bpre     = (int*)(ws + off);  off += 128 * 4;
  const bool bucket_ok = (off <= ws_size) && (nb8 <= 128 * SCAN_CHUNK);

  conv_w<<<128, 256, 0, stream>>>(w, wt);
  const int gemm_blocks = (n_nodes + GM_NODES - 1) / GM_NODES;
  gemm_mfma<<<gemm_blocks, 256, 0, stream>>>(x, wt, h, n_nodes);

  if (bucket_ok) {
    hipMemsetAsync(counts2, 0, (size_t)nb8 * 4, stream);
    const int eblocks = (n_edges + 255) / 256;
    hist2<<<eblocks, 256, 0, stream>>>(erows, counts2, n_edges);
    const int nb = (nb8 + SCAN_CHUNK - 1) / SCAN_CHUNK;
    reduce_chunks<<<nb, 256, 0, stream>>>(counts2, bsum, nb8);
    scan_bsums<<<1, 128, 0, stream>>>(bsum, bpre, offsets2, nb, nb8);
    write_offsets<<<nb, 256, 0, stream>>>(counts2, bpre, offsets2, cursor2, nb8);
    fill_buckets<<<eblocks, 256, 0, stream>>>(erows, ecols, evals, cursor2, bcv,
                                              n_edges);
    bucket_gather<<<nb_buckets, 256, 0, stream>>>(h, offsets2, bcv, bias, out,
                                                  n_nodes);
  } else {
    const int n4 = out_size / 4;
    init_bias<<<(n4 + 255) / 256, 256, 0, stream>>>(out, bias, n4);
    scatter_edges<<<(n_edges + 3) / 4, 256, 0, stream>>>(h, erows, ecols, evals,
                                                         out, n_edges);
  }
}

// Round 6
// 445.107 us; speedup vs baseline: 3.4326x; 3.4326x over previous
//
#include <hip/hip_runtime.h>

// GCNConv forward: out = segment_sum(vals * (x@W)[cols], rows) + bias
// Round 6: R5's LDS-atomic bucket_gather was latency-bound (CAS loops + low
// occupancy). Keep the dense bucket append (fill_buckets), add a cheap
// per-bucket counting sort to row-exact CSR, aggregate with R4's
// full-occupancy gather_nodes (no atomics, 4 gathers in flight).
//
// ws: h[N*128] bf16 | wt[128*264] bf16 | counts2[NB*8] | offsets2[NB*8+1] |
//     cursor2[NB*8] | bcv[E] int2 | sedge[E] int2 | offsets[NB*64+1] |
//     bsum[128] | bpre[128]

typedef __attribute__((ext_vector_type(8))) short short8;
typedef __attribute__((ext_vector_type(4))) float floatx4;

#define WT_K 264
#define GM_NODES 128
#define SCAN_CHUNK 1024
#define BSHIFT 6              // 64 rows per bucket
#define BROWS 64

static __device__ __forceinline__ uint f2bf(float x) {  // RNE f32->bf16 bits
  uint u = __float_as_uint(x);
  return (u + 0x7fffu + ((u >> 16) & 1u)) >> 16;
}

// ---- W[k][f] f32 -> wt[f][k] bf16 (k padded to WT_K) ----
__global__ __launch_bounds__(256) void conv_w(const float* __restrict__ w,
                                              ushort* __restrict__ wt) {
  const int f = blockIdx.x;
  const int k = threadIdx.x;
  wt[f * WT_K + k] = (ushort)f2bf(w[k * 128 + f]);
}

// ---- GEMM: h^T = W^T x^T via 16x16x32 bf16 MFMA ----
__global__ __launch_bounds__(256) void gemm_mfma(const float* __restrict__ x,
                                                 const ushort* __restrict__ wt,
                                                 ushort* __restrict__ h,
                                                 int n_nodes) {
  __shared__ ushort lw[128 * WT_K];
  __shared__ ushort xa[GM_NODES * 40];
  const int t = threadIdx.x;
  const int lane = t & 63;
  const int wq = t >> 6;
  const int quad = lane >> 4;
  const int l15 = lane & 15;
  const int row0 = blockIdx.x * GM_NODES;

  {
    const uint4* src = (const uint4*)wt;
    uint4* dst = (uint4*)lw;
    for (int i = t; i < (128 * WT_K * 2) / 16; i += 256) dst[i] = src[i];
  }

  floatx4 acc[2][8];
#pragma unroll
  for (int nt = 0; nt < 2; ++nt)
#pragma unroll
    for (int mt = 0; mt < 8; ++mt) acc[nt][mt] = (floatx4){0.f, 0.f, 0.f, 0.f};

  float4 cur[4];
#pragma unroll
  for (int i = 0; i < 4; ++i) {
    const int idx = i * 256 + t;
    const int row = idx >> 3, kq = idx & 7;
    const int gr = row0 + row;
    cur[i] = (gr < n_nodes) ? *(const float4*)&x[(size_t)gr * 256 + kq * 4]
                            : make_float4(0.f, 0.f, 0.f, 0.f);
  }

  for (int kc = 0; kc < 8; ++kc) {
#pragma unroll
    for (int i = 0; i < 4; ++i) {
      const int idx = i * 256 + t;
      const int row = idx >> 3, kq = idx & 7;
      uint2 p;
      p.x = f2bf(cur[i].x) | (f2bf(cur[i].y) << 16);
      p.y = f2bf(cur[i].z) | (f2bf(cur[i].w) << 16);
      *(uint2*)&xa[row * 40 + kq * 4] = p;
    }
    __syncthreads();

    float4 nxt[4];
    if (kc < 7) {
#pragma unroll
      for (int i = 0; i < 4; ++i) {
        const int idx = i * 256 + t;
        const int row = idx >> 3, kq = idx & 7;
        const int gr = row0 + row;
        nxt[i] = (gr < n_nodes)
                     ? *(const float4*)&x[(size_t)gr * 256 + (kc + 1) * 32 + kq * 4]
                     : make_float4(0.f, 0.f, 0.f, 0.f);
      }
    }

    short8 bfr[2];
    bfr[0] = *(const short8*)&xa[(wq * 32 + l15) * 40 + quad * 8];
    bfr[1] = *(const short8*)&xa[(wq * 32 + 16 + l15) * 40 + quad * 8];
#pragma unroll
    for (int mt = 0; mt < 8; ++mt) {
      const short8 afr =
          *(const short8*)&lw[(mt * 16 + l15) * WT_K + kc * 32 + quad * 8];
      acc[0][mt] = __builtin_amdgcn_mfma_f32_16x16x32_bf16(afr, bfr[0],
                                                           acc[0][mt], 0, 0, 0);
      acc[1][mt] = __builtin_amdgcn_mfma_f32_16x16x32_bf16(afr, bfr[1],
                                                           acc[1][mt], 0, 0, 0);
    }
    __syncthreads();
#pragma unroll
    for (int i = 0; i < 4; ++i) cur[i] = nxt[i];
  }

#pragma unroll
  for (int nt = 0; nt < 2; ++nt) {
    const int node = row0 + wq * 32 + nt * 16 + l15;
    if (node < n_nodes) {
#pragma unroll
      for (int mt = 0; mt < 8; ++mt) {
        uint2 p;
        p.x = f2bf(acc[nt][mt][0]) | (f2bf(acc[nt][mt][1]) << 16);
        p.y = f2bf(acc[nt][mt][2]) | (f2bf(acc[nt][mt][3]) << 16);
        *(uint2*)&h[(size_t)node * 128 + mt * 16 + quad * 4] = p;
      }
    }
  }
}

// ---- bucket histogram: counts2[(row>>6)*8 + blockIdx&7] ----
__global__ __launch_bounds__(256) void hist2(const int* __restrict__ erows,
                                             int* __restrict__ counts2,
                                             int n_edges) {
  int i = blockIdx.x * 256 + threadIdx.x;
  if (i < n_edges) {
    int slot = blockIdx.x & 7;
    atomicAdd(&counts2[((erows[i] >> BSHIFT) << 3) | slot], 1);
  }
}

// ---- 3-phase scan ----
__global__ __launch_bounds__(256) void reduce_chunks(const int* __restrict__ counts,
                                                     int* __restrict__ bsum, int n) {
  const int b = blockIdx.x;
  const int t = threadIdx.x;
  const int base = b * SCAN_CHUNK + t * 4;
  int s = 0;
  if (base + 4 <= n) {
    int4 v = *(const int4*)&counts[base];
    s = v.x + v.y + v.z + v.w;
  } else {
    for (int i = base; i < n; ++i) s += counts[i];
  }
#pragma unroll
  for (int off = 32; off; off >>= 1) s += __shfl_down(s, off, 64);
  __shared__ int wsum[4];
  if ((t & 63) == 0) wsum[t >> 6] = s;
  __syncthreads();
  if (t == 0) bsum[b] = wsum[0] + wsum[1] + wsum[2] + wsum[3];
}

__global__ __launch_bounds__(128) void scan_bsums(const int* __restrict__ bsum,
                                                  int* __restrict__ bpre,
                                                  int* __restrict__ offsets,
                                                  int nb, int n) {
  __shared__ int s[128];
  const int t = threadIdx.x;
  int v = (t < nb) ? bsum[t] : 0;
  s[t] = v;
  __syncthreads();
  for (int off = 1; off < 128; off <<= 1) {
    int u = (t >= off) ? s[t - off] : 0;
    __syncthreads();
    s[t] += u;
    __syncthreads();
  }
  if (t < nb) bpre[t] = s[t] - v;
  if (t == 0) offsets[n] = s[127];
}

__global__ __launch_bounds__(256) void write_offsets(const int* __restrict__ counts,
                                                     const int* __restrict__ bpre,
                                                     int* __restrict__ offsets,
                                                     int* __restrict__ cursor, int n) {
  const int b = blockIdx.x;
  const int t = threadIdx.x;
  const int base = b * SCAN_CHUNK + t * 4;
  int c0 = 0, c1 = 0, c2 = 0, c3 = 0;
  if (base + 4 <= n) {
    int4 v = *(const int4*)&counts[base];
    c0 = v.x; c1 = v.y; c2 = v.z; c3 = v.w;
  } else {
    if (base + 0 < n) c0 = counts[base + 0];
    if (base + 1 < n) c1 = counts[base + 1];
    if (base + 2 < n) c2 = counts[base + 2];
    if (base + 3 < n) c3 = counts[base + 3];
  }
  const int mysum = c0 + c1 + c2 + c3;
  __shared__ int sums[256];
  sums[t] = mysum;
  __syncthreads();
  for (int off = 1; off < 256; off <<= 1) {
    int u = (t >= off) ? sums[t - off] : 0;
    __syncthreads();
    sums[t] += u;
    __syncthreads();
  }
  int pre = bpre[b] + sums[t] - mysum;
  if (base + 0 < n) { offsets[base + 0] = pre; cursor[base + 0] = pre; pre += c0; }
  if (base + 1 < n) { offsets[base + 1] = pre; cursor[base + 1] = pre; pre += c1; }
  if (base + 2 < n) { offsets[base + 2] = pre; cursor[base + 2] = pre; pre += c2; }
  if (base + 3 < n) { offsets[base + 3] = pre; cursor[base + 3] = pre; pre += c3; }
}

// ---- append edges into (bucket,slot) regions; rowoff packed into col word ----
__global__ __launch_bounds__(256) void fill_buckets(
    const int* __restrict__ erows, const int* __restrict__ ecols,
    const float* __restrict__ evals, int* __restrict__ cursor2,
    int2* __restrict__ bcv, int n_edges) {
  int i = blockIdx.x * 256 + threadIdx.x;
  if (i < n_edges) {
    int slot = blockIdx.x & 7;
    int r = erows[i];
    int idx = ((r >> BSHIFT) << 3) | slot;
    int pos = atomicAdd(&cursor2[idx], 1);
    int2 p;
    p.x = ecols[i] | ((r & (BROWS - 1)) << 17);
    p.y = __float_as_int(evals[i]);
    bcv[pos] = p;
  }
}

// ---- per-bucket counting sort -> row-exact sedge + offsets ----
// One block per bucket (~1024 edges in an 8KB L2-resident region).
__global__ __launch_bounds__(256) void bucket_sort(
    const int* __restrict__ offsets2, const int2* __restrict__ bcv,
    int2* __restrict__ sedge, int* __restrict__ offsets, int nb_buckets) {
  __shared__ int cnt[BROWS];
  __shared__ int cur[BROWS];
  const int b = blockIdx.x;
  const int t = threadIdx.x;
  const int p0 = offsets2[b * 8];
  const int p1 = offsets2[b * 8 + 8];
  if (t < BROWS) cnt[t] = 0;
  __syncthreads();
  for (int i = p0 + t; i < p1; i += 256)
    atomicAdd(&cnt[((uint)bcv[i].x) >> 17], 1);   // native ds_add (int)
  __syncthreads();
  if (t < BROWS) {                                 // wave 0: 64-lane scan
    int c = cnt[t];
    int s = c;
#pragma unroll
    for (int off = 1; off < 64; off <<= 1) {
      int u = __shfl_up(s, off, 64);
      if (t >= off) s += u;
    }
    cur[t] = s - c;                                // exclusive prefix
    offsets[b * BROWS + t] = p0 + s - c;
  }
  if (t == 0 && b == nb_buckets - 1) offsets[nb_buckets * BROWS] = p1;
  __syncthreads();
  for (int i = p0 + t; i < p1; i += 256) {
    int2 rec = bcv[i];
    int r = ((uint)rec.x) >> 17;
    int pos = p0 + atomicAdd(&cur[r], 1);
    int2 o; o.x = rec.x & 0x1FFFF; o.y = rec.y;
    sedge[pos] = o;                                // dense 8KB region
  }
}

// ---- gather: out[node] = bias + sum val * h_bf16[col]; lane = feats 2l,2l+1 ----
__global__ __launch_bounds__(256) void gather_nodes(
    const ushort* __restrict__ h, const int* __restrict__ offsets,
    const int2* __restrict__ sedge, const float* __restrict__ bias,
    float* __restrict__ out, int n_nodes) {
  int node = blockIdx.x * 4 + (threadIdx.x >> 6);
  if (node >= n_nodes) return;
  int lane = threadIdx.x & 63;
  float2 acc = ((const float2*)bias)[lane];
  int p = offsets[node];
  const int p1 = offsets[node + 1];
  for (; p + 4 <= p1; p += 4) {
    int2 e0 = sedge[p + 0];
    int2 e1 = sedge[p + 1];
    int2 e2 = sedge[p + 2];
    int2 e3 = sedge[p + 3];
    uint u0 = ((const uint*)(h + (size_t)e0.x * 128))[lane];
    uint u1 = ((const uint*)(h + (size_t)e1.x * 128))[lane];
    uint u2 = ((const uint*)(h + (size_t)e2.x * 128))[lane];
    uint u3 = ((const uint*)(h + (size_t)e3.x * 128))[lane];
    float v0 = __int_as_float(e0.y), v1 = __int_as_float(e1.y);
    float v2 = __int_as_float(e2.y), v3 = __int_as_float(e3.y);
    acc.x += v0 * __uint_as_float(u0 << 16);
    acc.y += v0 * __uint_as_float(u0 & 0xffff0000u);
    acc.x += v1 * __uint_as_float(u1 << 16);
    acc.y += v1 * __uint_as_float(u1 & 0xffff0000u);
    acc.x += v2 * __uint_as_float(u2 << 16);
    acc.y += v2 * __uint_as_float(u2 & 0xffff0000u);
    acc.x += v3 * __uint_as_float(u3 << 16);
    acc.y += v3 * __uint_as_float(u3 & 0xffff0000u);
  }
  for (; p < p1; ++p) {
    int2 ev = sedge[p];
    float v = __int_as_float(ev.y);
    uint u = ((const uint*)(h + (size_t)ev.x * 128))[lane];
    acc.x += v * __uint_as_float(u << 16);
    acc.y += v * __uint_as_float(u & 0xffff0000u);
  }
  ((float2*)(out + (size_t)node * 128))[lane] = acc;
}

// ---- fallback (small ws): bias init + atomic scatter on bf16 h ----
__global__ __launch_bounds__(256) void init_bias(float* __restrict__ out,
                                                 const float* __restrict__ bias,
                                                 int n4) {
  int i = blockIdx.x * 256 + threadIdx.x;
  if (i < n4) {
    float4 b = ((const float4*)bias)[i & 31];
    ((float4*)out)[i] = b;
  }
}

__global__ __launch_bounds__(256) void scatter_edges(
    const ushort* __restrict__ h, const int* __restrict__ erows,
    const int* __restrict__ ecols, const float* __restrict__ evals,
    float* __restrict__ out, int n_edges) {
  int e = blockIdx.x * 4 + (threadIdx.x >> 6);
  if (e >= n_edges) return;
  int lane = threadIdx.x & 63;
  int row = erows[e];
  int col = ecols[e];
  float v = evals[e];
  uint u = ((const uint*)(h + (size_t)col * 128))[lane];
  float* op = out + (size_t)row * 128 + lane * 2;
  atomicAdd(op, v * __uint_as_float(u << 16));
  atomicAdd(op + 1, v * __uint_as_float(u & 0xffff0000u));
}

extern "C" void kernel_launch(void* const* d_in, const int* in_sizes, int n_in,
                              void* d_out, int out_size, void* d_ws, size_t ws_size,
                              hipStream_t stream) {
  const float* x     = (const float*)d_in[0];
  const int*   erows = (const int*)d_in[1];
  const int*   ecols = (const int*)d_in[2];
  const float* evals = (const float*)d_in[3];
  const float* w     = (const float*)d_in[4];
  const float* bias  = (const float*)d_in[5];
  float* out = (float*)d_out;

  const int n_nodes = in_sizes[0] / 256;
  const int n_edges = in_sizes[1];
  const int nb_buckets = (n_nodes + BROWS - 1) >> BSHIFT;
  const int nb8 = nb_buckets * 8;

  // ws carve-up (16B aligned)
  char* ws = (char*)d_ws;
  size_t off = 0;
  ushort* h  = (ushort*)(ws + off);  off += ((size_t)n_nodes * 128 * 2 + 15) & ~15ull;
  ushort* wt = (ushort*)(ws + off);  off += ((size_t)128 * WT_K * 2 + 15) & ~15ull;
  int* counts2  = (int*)(ws + off);  off += ((size_t)nb8 * 4 + 15) & ~15ull;
  int* offsets2 = (int*)(ws + off);  off += ((size_t)(nb8 + 1) * 4 + 15) & ~15ull;
  int* cursor2  = (int*)(ws + off);  off += ((size_t)nb8 * 4 + 15) & ~15ull;
  int2* bcv     = (int2*)(ws + off); off += (size_t)n_edges * 8;
  int2* sedge   = (int2*)(ws + off); off += (size_t)n_edges * 8;
  int* offsets  = (int*)(ws + off);  off += ((size_t)(nb_buckets * BROWS + 1) * 4 + 15) & ~15ull;
  int* bsum     = (int*)(ws + off);  off += 128 * 4;
  int* bpre     = (int*)(ws + off);  off += 128 * 4;
  const bool bucket_ok = (off <= ws_size) && (nb8 <= 128 * SCAN_CHUNK) &&
                         (n_nodes <= (1 << 17));

  conv_w<<<128, 256, 0, stream>>>(w, wt);
  const int gemm_blocks = (n_nodes + GM_NODES - 1) / GM_NODES;
  gemm_mfma<<<gemm_blocks, 256, 0, stream>>>(x, wt, h, n_nodes);

  if (bucket_ok) {
    hipMemsetAsync(counts2, 0, (size_t)nb8 * 4, stream);
    const int eblocks = (n_edges + 255) / 256;
    hist2<<<eblocks, 256, 0, stream>>>(erows, counts2, n_edges);
    const int nb = (nb8 + SCAN_CHUNK - 1) / SCAN_CHUNK;
    reduce_chunks<<<nb, 256, 0, stream>>>(counts2, bsum, nb8);
    scan_bsums<<<1, 128, 0, stream>>>(bsum, bpre, offsets2, nb, nb8);
    write_offsets<<<nb, 256, 0, stream>>>(counts2, bpre, offsets2, cursor2, nb8);
    fill_buckets<<<eblocks, 256, 0, stream>>>(erows, ecols, evals, cursor2, bcv,
                                              n_edges);
    bucket_sort<<<nb_buckets, 256, 0, stream>>>(offsets2, bcv, sedge, offsets,
                                                nb_buckets);
    gather_nodes<<<(n_nodes + 3) / 4, 256, 0, stream>>>(h, offsets, sedge, bias,
                                                        out, n_nodes);
  } else {
    const int n4 = out_size / 4;
    init_bias<<<(n4 + 255) / 256, 256, 0, stream>>>(out, bias, n4);
    scatter_edges<<<(n_edges + 3) / 4, 256, 0, stream>>>(h, erows, ecols, evals,
                                                         out, n_edges);
  }
}

// Round 7
// 352.651 us; speedup vs baseline: 4.3325x; 1.2622x over previous
//
#include <hip/hip_runtime.h>

// GCNConv forward: out = segment_sum(vals * (x@W)[cols], rows) + bias
// Round 7: slot = REAL XCD id via s_getreg(HW_REG_XCC_ID) (m09-verified).
// Fixed-capacity (bucket,xcd) append regions -> no pre-count/scan kernels at
// all; overflow spill list for safety. sort_gather fuses per-bucket counting
// sort (LDS) + node gather (kills the 25.6MB sedge round-trip).
//
// ws: h[N*128] bf16 | wt[128*264] bf16 | cursor3[NB*8+1] (last = ovf_cnt) |
//     bcv[NB*8*CAP] int2 | ovf[OVFCAP] int4

typedef __attribute__((ext_vector_type(8))) short short8;
typedef __attribute__((ext_vector_type(4))) float floatx4;

#define WT_K 264
#define GM_NODES 128
#define BSHIFT 6              // 64 rows per bucket
#define BROWS 64
#define CAP 256               // records per (bucket,xcd) region; mean 128, 11 sigma
#define OVFCAP 65536
// s_getreg imm: id=20 (HW_REG_XCC_ID), offset=0, size=4 -> (3<<11)|20
#define XCC_GETREG_IMM 6164

static __device__ __forceinline__ uint f2bf(float x) {  // RNE f32->bf16 bits
  uint u = __float_as_uint(x);
  return (u + 0x7fffu + ((u >> 16) & 1u)) >> 16;
}

// ---- W[k][f] f32 -> wt[f][k] bf16 (k padded to WT_K) ----
__global__ __launch_bounds__(256) void conv_w(const float* __restrict__ w,
                                              ushort* __restrict__ wt) {
  const int f = blockIdx.x;
  const int k = threadIdx.x;
  wt[f * WT_K + k] = (ushort)f2bf(w[k * 128 + f]);
}

// ---- GEMM: h^T = W^T x^T via 16x16x32 bf16 MFMA ----
__global__ __launch_bounds__(256) void gemm_mfma(const float* __restrict__ x,
                                                 const ushort* __restrict__ wt,
                                                 ushort* __restrict__ h,
                                                 int n_nodes) {
  __shared__ ushort lw[128 * WT_K];
  __shared__ ushort xa[GM_NODES * 40];
  const int t = threadIdx.x;
  const int lane = t & 63;
  const int wq = t >> 6;
  const int quad = lane >> 4;
  const int l15 = lane & 15;
  const int row0 = blockIdx.x * GM_NODES;

  {
    const uint4* src = (const uint4*)wt;
    uint4* dst = (uint4*)lw;
    for (int i = t; i < (128 * WT_K * 2) / 16; i += 256) dst[i] = src[i];
  }

  floatx4 acc[2][8];
#pragma unroll
  for (int nt = 0; nt < 2; ++nt)
#pragma unroll
    for (int mt = 0; mt < 8; ++mt) acc[nt][mt] = (floatx4){0.f, 0.f, 0.f, 0.f};

  float4 cur[4];
#pragma unroll
  for (int i = 0; i < 4; ++i) {
    const int idx = i * 256 + t;
    const int row = idx >> 3, kq = idx & 7;
    const int gr = row0 + row;
    cur[i] = (gr < n_nodes) ? *(const float4*)&x[(size_t)gr * 256 + kq * 4]
                            : make_float4(0.f, 0.f, 0.f, 0.f);
  }

  for (int kc = 0; kc < 8; ++kc) {
#pragma unroll
    for (int i = 0; i < 4; ++i) {
      const int idx = i * 256 + t;
      const int row = idx >> 3, kq = idx & 7;
      uint2 p;
      p.x = f2bf(cur[i].x) | (f2bf(cur[i].y) << 16);
      p.y = f2bf(cur[i].z) | (f2bf(cur[i].w) << 16);
      *(uint2*)&xa[row * 40 + kq * 4] = p;
    }
    __syncthreads();

    float4 nxt[4];
    if (kc < 7) {
#pragma unroll
      for (int i = 0; i < 4; ++i) {
        const int idx = i * 256 + t;
        const int row = idx >> 3, kq = idx & 7;
        const int gr = row0 + row;
        nxt[i] = (gr < n_nodes)
                     ? *(const float4*)&x[(size_t)gr * 256 + (kc + 1) * 32 + kq * 4]
                     : make_float4(0.f, 0.f, 0.f, 0.f);
      }
    }

    short8 bfr[2];
    bfr[0] = *(const short8*)&xa[(wq * 32 + l15) * 40 + quad * 8];
    bfr[1] = *(const short8*)&xa[(wq * 32 + 16 + l15) * 40 + quad * 8];
#pragma unroll
    for (int mt = 0; mt < 8; ++mt) {
      const short8 afr =
          *(const short8*)&lw[(mt * 16 + l15) * WT_K + kc * 32 + quad * 8];
      acc[0][mt] = __builtin_amdgcn_mfma_f32_16x16x32_bf16(afr, bfr[0],
                                                           acc[0][mt], 0, 0, 0);
      acc[1][mt] = __builtin_amdgcn_mfma_f32_16x16x32_bf16(afr, bfr[1],
                                                           acc[1][mt], 0, 0, 0);
    }
    __syncthreads();
#pragma unroll
    for (int i = 0; i < 4; ++i) cur[i] = nxt[i];
  }

#pragma unroll
  for (int nt = 0; nt < 2; ++nt) {
    const int node = row0 + wq * 32 + nt * 16 + l15;
    if (node < n_nodes) {
#pragma unroll
      for (int mt = 0; mt < 8; ++mt) {
        uint2 p;
        p.x = f2bf(acc[nt][mt][0]) | (f2bf(acc[nt][mt][1]) << 16);
        p.y = f2bf(acc[nt][mt][2]) | (f2bf(acc[nt][mt][3]) << 16);
        *(uint2*)&h[(size_t)node * 128 + mt * 16 + quad * 4] = p;
      }
    }
  }
}

// ---- append edges into (bucket, true-XCD) regions; rowoff packed in col ----
__global__ __launch_bounds__(256) void fill_xcd(
    const int* __restrict__ erows, const int* __restrict__ ecols,
    const float* __restrict__ evals, int* __restrict__ cursor3,
    int2* __restrict__ bcv, int* __restrict__ ovf_cnt,
    int4* __restrict__ ovf, int n_edges) {
  int i = blockIdx.x * 256 + threadIdx.x;
  if (i >= n_edges) return;
  const int xcd = (int)(__builtin_amdgcn_s_getreg(XCC_GETREG_IMM)) & 7;
  const int r = erows[i];
  const int c = ecols[i];
  const float v = evals[i];
  const int reg = ((r >> BSHIFT) << 3) | xcd;
  const int pos = atomicAdd(&cursor3[reg], 1);
  if (pos < CAP) {
    int2 p;
    p.x = c | ((r & (BROWS - 1)) << 17);
    p.y = __float_as_int(v);
    bcv[(size_t)reg * CAP + pos] = p;
  } else {
    int op = atomicAdd(ovf_cnt, 1);
    if (op < OVFCAP) {
      int4 q; q.x = r; q.y = c; q.z = __float_as_int(v); q.w = 0;
      ovf[op] = q;
    }
  }
}

// ---- fused per-bucket counting sort (LDS) + node gather ----
// One block per bucket: sort <=2048 records into 16KB LDS, then 4 waves
// gather 16 nodes each (lane = feature pair), write dense out rows + bias.
__global__ __launch_bounds__(256) void sort_gather(
    const ushort* __restrict__ h, const int* __restrict__ cursor3,
    const int2* __restrict__ bcv, const float* __restrict__ bias,
    float* __restrict__ out, int n_nodes) {
  __shared__ int2 buf[8 * CAP];            // 16 KB sorted records
  __shared__ int cnt[BROWS], start[BROWS], cur[BROWS];
  __shared__ int scnt[8];
  const int b = blockIdx.x;
  const int t = threadIdx.x;
  if (t < 8) scnt[t] = min(cursor3[b * 8 + t], CAP);
  if (t < BROWS) cnt[t] = 0;
  __syncthreads();

  // histogram of within-bucket row offsets (native int ds_add)
#pragma unroll
  for (int x = 0; x < 8; ++x) {
    const int n = scnt[x];
    const int2* src = &bcv[(size_t)(b * 8 + x) * CAP];
    for (int i = t; i < n; i += 256) atomicAdd(&cnt[((uint)src[i].x) >> 17], 1);
  }
  __syncthreads();

  if (t < BROWS) {   // wave 0: 64-lane inclusive scan -> exclusive starts
    int c = cnt[t];
    int s = c;
#pragma unroll
    for (int off = 1; off < 64; off <<= 1) {
      int u = __shfl_up(s, off, 64);
      if (t >= off) s += u;
    }
    start[t] = s - c;
    cur[t] = s - c;
  }
  __syncthreads();

  // scatter into row-sorted LDS buffer
#pragma unroll
  for (int x = 0; x < 8; ++x) {
    const int n = scnt[x];
    const int2* src = &bcv[(size_t)(b * 8 + x) * CAP];
    for (int i = t; i < n; i += 256) {
      int2 rec = src[i];
      int pos = atomicAdd(&cur[((uint)rec.x) >> 17], 1);
      buf[pos] = rec;
    }
  }
  __syncthreads();

  // gather: wave w handles rows w*16 .. w*16+15
  const int lane = t & 63;
  const int w = t >> 6;
  const float2 bv = ((const float2*)bias)[lane];
  for (int rr = w * 16; rr < w * 16 + 16; ++rr) {
    const int node = b * BROWS + rr;
    if (node >= n_nodes) break;
    float2 acc = bv;
    int p = start[rr];
    const int p1 = start[rr] + cnt[rr];
    for (; p + 4 <= p1; p += 4) {
      int2 e0 = buf[p + 0];
      int2 e1 = buf[p + 1];
      int2 e2 = buf[p + 2];
      int2 e3 = buf[p + 3];
      uint u0 = ((const uint*)(h + (size_t)(e0.x & 0x1FFFF) * 128))[lane];
      uint u1 = ((const uint*)(h + (size_t)(e1.x & 0x1FFFF) * 128))[lane];
      uint u2 = ((const uint*)(h + (size_t)(e2.x & 0x1FFFF) * 128))[lane];
      uint u3 = ((const uint*)(h + (size_t)(e3.x & 0x1FFFF) * 128))[lane];
      float v0 = __int_as_float(e0.y), v1 = __int_as_float(e1.y);
      float v2 = __int_as_float(e2.y), v3 = __int_as_float(e3.y);
      acc.x += v0 * __uint_as_float(u0 << 16);
      acc.y += v0 * __uint_as_float(u0 & 0xffff0000u);
      acc.x += v1 * __uint_as_float(u1 << 16);
      acc.y += v1 * __uint_as_float(u1 & 0xffff0000u);
      acc.x += v2 * __uint_as_float(u2 << 16);
      acc.y += v2 * __uint_as_float(u2 & 0xffff0000u);
      acc.x += v3 * __uint_as_float(u3 << 16);
      acc.y += v3 * __uint_as_float(u3 & 0xffff0000u);
    }
    for (; p < p1; ++p) {
      int2 ev = buf[p];
      float v = __int_as_float(ev.y);
      uint u = ((const uint*)(h + (size_t)(ev.x & 0x1FFFF) * 128))[lane];
      acc.x += v * __uint_as_float(u << 16);
      acc.y += v * __uint_as_float(u & 0xffff0000u);
    }
    ((float2*)(out + (size_t)node * 128))[lane] = acc;
  }
}

// ---- drain overflow spill list (expected empty; fixed grid for graph) ----
__global__ __launch_bounds__(256) void ovf_scatter(
    const ushort* __restrict__ h, const int* __restrict__ ovf_cnt,
    const int4* __restrict__ ovf, float* __restrict__ out) {
  const int n = min(*ovf_cnt, OVFCAP);
  const int lane = threadIdx.x & 63;
  const int wid = (blockIdx.x * 256 + threadIdx.x) >> 6;
  const int nw = gridDim.x * 4;
  for (int e = wid; e < n; e += nw) {
    int4 rec = ovf[e];
    float v = __int_as_float(rec.z);
    uint u = ((const uint*)(h + (size_t)rec.y * 128))[lane];
    float* op = out + (size_t)rec.x * 128 + lane * 2;
    atomicAdd(op, v * __uint_as_float(u << 16));
    atomicAdd(op + 1, v * __uint_as_float(u & 0xffff0000u));
  }
}

// ---- fallback (small ws): bias init + atomic scatter on bf16 h ----
__global__ __launch_bounds__(256) void init_bias(float* __restrict__ out,
                                                 const float* __restrict__ bias,
                                                 int n4) {
  int i = blockIdx.x * 256 + threadIdx.x;
  if (i < n4) {
    float4 b = ((const float4*)bias)[i & 31];
    ((float4*)out)[i] = b;
  }
}

__global__ __launch_bounds__(256) void scatter_edges(
    const ushort* __restrict__ h, const int* __restrict__ erows,
    const int* __restrict__ ecols, const float* __restrict__ evals,
    float* __restrict__ out, int n_edges) {
  int e = blockIdx.x * 4 + (threadIdx.x >> 6);
  if (e >= n_edges) return;
  int lane = threadIdx.x & 63;
  int row = erows[e];
  int col = ecols[e];
  float v = evals[e];
  uint u = ((const uint*)(h + (size_t)col * 128))[lane];
  float* op = out + (size_t)row * 128 + lane * 2;
  atomicAdd(op, v * __uint_as_float(u << 16));
  atomicAdd(op + 1, v * __uint_as_float(u & 0xffff0000u));
}

extern "C" void kernel_launch(void* const* d_in, const int* in_sizes, int n_in,
                              void* d_out, int out_size, void* d_ws, size_t ws_size,
                              hipStream_t stream) {
  const float* x     = (const float*)d_in[0];
  const int*   erows = (const int*)d_in[1];
  const int*   ecols = (const int*)d_in[2];
  const float* evals = (const float*)d_in[3];
  const float* w     = (const float*)d_in[4];
  const float* bias  = (const float*)d_in[5];
  float* out = (float*)d_out;

  const int n_nodes = in_sizes[0] / 256;
  const int n_edges = in_sizes[1];
  const int nb_buckets = (n_nodes + BROWS - 1) >> BSHIFT;
  const int nb8 = nb_buckets * 8;

  // ws carve-up (16B aligned)
  char* ws = (char*)d_ws;
  size_t off = 0;
  ushort* h  = (ushort*)(ws + off);  off += ((size_t)n_nodes * 128 * 2 + 15) & ~15ull;
  ushort* wt = (ushort*)(ws + off);  off += ((size_t)128 * WT_K * 2 + 15) & ~15ull;
  int* cursor3 = (int*)(ws + off);   off += ((size_t)(nb8 + 1) * 4 + 15) & ~15ull;
  int2* bcv    = (int2*)(ws + off);  off += (size_t)nb8 * CAP * 8;
  int4* ovf    = (int4*)(ws + off);  off += (size_t)OVFCAP * 16;
  const bool bucket_ok = (off <= ws_size) && (n_nodes <= (1 << 17));
  int* ovf_cnt = cursor3 + nb8;

  conv_w<<<128, 256, 0, stream>>>(w, wt);
  const int gemm_blocks = (n_nodes + GM_NODES - 1) / GM_NODES;
  gemm_mfma<<<gemm_blocks, 256, 0, stream>>>(x, wt, h, n_nodes);

  if (bucket_ok) {
    hipMemsetAsync(cursor3, 0, (size_t)(nb8 + 1) * 4, stream);
    const int eblocks = (n_edges + 255) / 256;
    fill_xcd<<<eblocks, 256, 0, stream>>>(erows, ecols, evals, cursor3, bcv,
                                          ovf_cnt, ovf, n_edges);
    sort_gather<<<nb_buckets, 256, 0, stream>>>(h, cursor3, bcv, bias, out,
                                                n_nodes);
    ovf_scatter<<<32, 256, 0, stream>>>(h, ovf_cnt, ovf, out);
  } else {
    const int n4 = out_size / 4;
    init_bias<<<(n4 + 255) / 256, 256, 0, stream>>>(out, bias, n4);
    scatter_edges<<<(n_edges + 3) / 4, 256, 0, stream>>>(h, erows, ecols, evals,
                                                         out, n_edges);
  }
}